// Round 5
// baseline (746.403 us; speedup 1.0000x reference)
//
#include <hip/hip_runtime.h>

// Problem constants (fixed by setup_inputs)
#define M_DIM 4096
#define K_DIM 4096
#define N_DIM 12288
// GEMM tile (round-0 proven geometry)
#define BM 256
#define BN 128
#define BK 64
#define NT (K_DIM / BK)   // 64 K-tiles

typedef __bf16 bf16x8  __attribute__((ext_vector_type(8)));
typedef float  floatx16 __attribute__((ext_vector_type(16)));

// ---------------- x fp32 -> bf16 ----------------
__global__ __launch_bounds__(256) void xcast_kernel(const float* __restrict__ x,
                                                    __bf16* __restrict__ xb) {
    int idx = blockIdx.x * 256 + threadIdx.x;      // each thread: 8 floats
    const float4* xv = (const float4*)x;
    float4 a = xv[idx * 2];
    float4 b = xv[idx * 2 + 1];
    bf16x8 o;
    o[0] = (__bf16)a.x; o[1] = (__bf16)a.y; o[2] = (__bf16)a.z; o[3] = (__bf16)a.w;
    o[4] = (__bf16)b.x; o[5] = (__bf16)b.y; o[6] = (__bf16)b.z; o[7] = (__bf16)b.w;
    ((bf16x8*)xb)[idx] = o;
}

// ---------------- fused W4 GEMM: C[M,N] = A[M,K] * dequant(Q)[N,K]^T + bias --
// Round-0 structure (measured 440 us): 256x128 tile, BK=64, 4 waves each
// 128x64 via 4x2 mfma_f32_32x32x16_bf16; single-buffered LDS, 2 barriers/tile.
// NEW: dequant fused. qweight is int32 [N, K/2], ONE byte (2 nibbles) per
// int32 -> 4 consecutive int32 = 8 k-values = one bf16x8 fragment.
// B path is reg-staged (T14 async-split): int4 prefetch issued during tile
// t-1's compute phase (latency hidden under MFMA), dequant (~128 VALU/thread,
// VALU pipe was 8% busy) + ds_write_b128 into the SAME physical swizzled
// layout the round-0 reads expect: elem(row, blk) at row*64 + (blk^g(row))*8,
// g(row) = (row&7) ^ (((row>>3)&3)<<1). A path unchanged: global_load_lds
// with pre-swizzled source. Eliminates the standalone dequant kernel
// (96 MB read + 96 MB write + 96 MB re-read).
__global__ __launch_bounds__(256, 2) void gemm_kernel(const __bf16* __restrict__ A,
                                                      const int* __restrict__ Q,
                                                      const float* __restrict__ scales,
                                                      const float* __restrict__ zeros,
                                                      const float* __restrict__ bias,
                                                      float* __restrict__ C) {
    __shared__ __bf16 As[BM * BK];   // 32 KB
    __shared__ __bf16 Bs[BN * BK];   // 16 KB

    const int tid  = threadIdx.x;
    const int wave = tid >> 6;
    const int lane = tid & 63;
    const int l32  = lane & 31;
    const int half = lane >> 5;
    const int wm = (wave >> 1) * 128;    // wave's m offset (0 or 128)
    const int wn = (wave & 1) * 64;      // wave's n offset (0 or 64)

    // XCD-aware bijective swizzle: 1536 blocks = 8 XCDs x 192
    // (12 B-panels x 16 M-tiles per XCD chunk; B-panel L2-resident).
    const int bid = blockIdx.y * 16 + blockIdx.x;   // x fastest at dispatch
    const int sw  = (bid & 7) * 192 + (bid >> 3);
    const int bm0 = (sw & 15) * BM;                  // M fastest within chunk
    const int bn0 = (sw >> 4) * BN;

    // ---- A staging constants (round-0 verbatim) ----
    const int rowInChunk = lane >> 3;                 // 0..7
    const int slot       = lane & 7;
    const int gread      = (l32 & 7) ^ (((l32 >> 3) & 3) << 1);

    // ---- fused-B constants ----
    const int brow = tid >> 1;                        // 0..127 (B row in tile)
    const int hk   = tid & 1;                         // k-half (32 elems)
    const int gr   = (brow & 7) ^ (((brow >> 3) & 3) << 1);
    const int ncol = bn0 + brow;                      // output col / Q row
    const int* qrow = Q + (size_t)ncol * (K_DIM / 2) + hk * 16;
    __bf16* bdst = Bs + brow * 64;
    // phys 16B-slot for logical blk (hk*4+j): ((hk*4+j) ^ gr)

    floatx16 acc[4][2] = {};

    // Prologue: prefetch B regs + scale/zero for tile 0.
    int4 q0 = *(const int4*)(qrow + 0);
    int4 q1 = *(const int4*)(qrow + 4);
    int4 q2 = *(const int4*)(qrow + 8);
    int4 q3 = *(const int4*)(qrow + 12);
    float scur = scales[ncol];
    float zcur = zeros[ncol];

    // Dequant one int4 (4 int32 = 8 nibbles) -> one bf16x8, store swizzled.
    #define DQW(Q4, J) { bf16x8 o; \
        o[0] = (__bf16)(((float)((Q4).x & 15)        - zcur) * scur); \
        o[1] = (__bf16)(((float)(((Q4).x >> 4) & 15) - zcur) * scur); \
        o[2] = (__bf16)(((float)((Q4).y & 15)        - zcur) * scur); \
        o[3] = (__bf16)(((float)(((Q4).y >> 4) & 15) - zcur) * scur); \
        o[4] = (__bf16)(((float)((Q4).z & 15)        - zcur) * scur); \
        o[5] = (__bf16)(((float)(((Q4).z >> 4) & 15) - zcur) * scur); \
        o[6] = (__bf16)(((float)((Q4).w & 15)        - zcur) * scur); \
        o[7] = (__bf16)(((float)(((Q4).w >> 4) & 15) - zcur) * scur); \
        *(bf16x8*)(bdst + (((hk * 4 + (J)) ^ gr) << 3)) = o; }

    for (int kt = 0; kt < NT; ++kt) {
        const int k0 = kt * BK;
        // A: 32 chunks of 8 rows; 8 per wave (global_load_lds, pre-swizzled src)
        #pragma unroll
        for (int r = 0; r < 8; ++r) {
            const int chunk = wave * 8 + r;
            const int row   = chunk * 8 + rowInChunk;
            const int kblk  = slot ^ rowInChunk ^ ((r & 3) << 1);
            const __bf16* ga = A + (size_t)(bm0 + row) * K_DIM + k0 + kblk * 8;
            __builtin_amdgcn_global_load_lds(
                (const __attribute__((address_space(1))) void*)ga,
                (__attribute__((address_space(3))) void*)(As + chunk * 512), 16, 0, 0);
        }
        // B: dequant tile-t regs -> LDS (overlaps with A gloads in flight)
        DQW(q0, 0); DQW(q1, 1); DQW(q2, 2); DQW(q3, 3);
        __syncthreads();

        // Prefetch tile t+1's B regs + scale/zero: lands during compute below.
        const int kn = (kt + 1) & (NT - 1);          // wrap: dead data, in-bounds
        const int cb = kn * 32;
        q0 = *(const int4*)(qrow + cb + 0);
        q1 = *(const int4*)(qrow + cb + 4);
        q2 = *(const int4*)(qrow + cb + 8);
        q3 = *(const int4*)(qrow + cb + 12);
        scur = scales[(kn >> 1) * N_DIM + ncol];
        zcur = zeros[(kn >> 1) * N_DIM + ncol];

        #pragma unroll
        for (int ks = 0; ks < 4; ++ks) {              // 4 k-steps of 16
            const int blk = ks * 2 + half;            // logical 16B-block along BK
            const int off = (blk ^ gread) << 3;       // swizzled element offset
            bf16x8 af[4], bfr[2];
            #pragma unroll
            for (int i = 0; i < 4; ++i)
                af[i] = *(const bf16x8*)(As + (wm + i * 32 + l32) * BK + off);
            #pragma unroll
            for (int t = 0; t < 2; ++t)
                bfr[t] = *(const bf16x8*)(Bs + (wn + t * 32 + l32) * BK + off);
            #pragma unroll
            for (int mi = 0; mi < 4; ++mi)
                #pragma unroll
                for (int ni = 0; ni < 2; ++ni)
                    acc[mi][ni] = __builtin_amdgcn_mfma_f32_32x32x16_bf16(
                        af[mi], bfr[ni], acc[mi][ni], 0, 0, 0);
        }
        __syncthreads();
    }

    // Epilogue: 32x32 C/D layout: col = lane&31, row = (reg&3)+8*(reg>>2)+4*half.
    #pragma unroll
    for (int ni = 0; ni < 2; ++ni) {
        const int col = bn0 + wn + ni * 32 + l32;
        const float bv = bias[col];
        #pragma unroll
        for (int mi = 0; mi < 4; ++mi) {
            #pragma unroll
            for (int reg = 0; reg < 16; ++reg) {
                const int row = bm0 + wm + mi * 32 + half * 4 + (reg & 3) + 8 * (reg >> 2);
                C[(size_t)row * N_DIM + col] = acc[mi][ni][reg] + bv;
            }
        }
    }
}

extern "C" void kernel_launch(void* const* d_in, const int* in_sizes, int n_in,
                              void* d_out, int out_size, void* d_ws, size_t ws_size,
                              hipStream_t stream) {
    const float* x      = (const float*)d_in[0];
    const int*   qw     = (const int*)d_in[1];
    const float* scales = (const float*)d_in[2];
    const float* zeros  = (const float*)d_in[3];
    const float* bias   = (const float*)d_in[4];
    float* out = (float*)d_out;

    // Workspace: [xb: M*K bf16 = 32 MiB] (dequant workspace eliminated)
    __bf16* xb = (__bf16*)d_ws;

    xcast_kernel<<<(M_DIM * K_DIM / 8) / 256, 256, 0, stream>>>(x, xb);

    dim3 grid(M_DIM / BM, N_DIM / BN);   // (16, 96)
    gemm_kernel<<<grid, 256, 0, stream>>>(xb, qw, scales, zeros, bias, out);
}

// Round 6
// 739.540 us; speedup vs baseline: 1.0093x; 1.0093x over previous
//
#include <hip/hip_runtime.h>

// Problem constants (fixed by setup_inputs)
#define M_DIM 4096
#define K_DIM 4096
#define N_DIM 12288
// GEMM tile (round-0 proven geometry)
#define BM 256
#define BN 128
#define BK 64
#define NT (K_DIM / BK)   // 64 K-tiles

typedef __bf16 bf16x8  __attribute__((ext_vector_type(8)));
typedef float  floatx16 __attribute__((ext_vector_type(16)));

// ---------------- x fp32 -> bf16 ----------------
__global__ __launch_bounds__(256) void xcast_kernel(const float* __restrict__ x,
                                                    __bf16* __restrict__ xb) {
    int idx = blockIdx.x * 256 + threadIdx.x;      // each thread: 8 floats
    const float4* xv = (const float4*)x;
    float4 a = xv[idx * 2];
    float4 b = xv[idx * 2 + 1];
    bf16x8 o;
    o[0] = (__bf16)a.x; o[1] = (__bf16)a.y; o[2] = (__bf16)a.z; o[3] = (__bf16)a.w;
    o[4] = (__bf16)b.x; o[5] = (__bf16)b.y; o[6] = (__bf16)b.z; o[7] = (__bf16)b.w;
    ((bf16x8*)xb)[idx] = o;
}

// ---------------- fused W4 GEMM: C[M,N] = A[M,K] * dequant(Q)[N,K]^T + bias --
// Round-0 skeleton (measured 440 us): 256x128 tile, BK=64, 4 waves each
// 128x64 via 4x2 mfma_f32_32x32x16_bf16; As single-buffered, 2 barriers/tile.
// Round-5 lesson: dequant placed in the STAGING phase serialized with MFMA
// (VALUBusy 24.6% additive, gemm +108us). Fix: Bs ping-pong; the 4 DQW
// fragments for tile t+1 are interleaved INSIDE the k-step MFMA loop of
// tile t (VALU/ds_write co-issue with the MFMA pipe, m114), and the q int4
// prefetch for tile t+2 is issued at the top of the compute phase (full
// compute-phase latency cover, double-set ping-pong regs).
// B physical layout identical to round 0: elem(row, blk) at
// row*64 + (blk^g(row))*8, g(row) = (row&7) ^ (((row>>3)&3)<<1).
__global__ __launch_bounds__(256, 2) void gemm_kernel(const __bf16* __restrict__ A,
                                                      const int* __restrict__ Q,
                                                      const float* __restrict__ scales,
                                                      const float* __restrict__ zeros,
                                                      const float* __restrict__ bias,
                                                      float* __restrict__ C) {
    __shared__ __bf16 As[BM * BK];        // 32 KB
    __shared__ __bf16 Bs[2][BN * BK];     // 2 x 16 KB

    const int tid  = threadIdx.x;
    const int wave = tid >> 6;
    const int lane = tid & 63;
    const int l32  = lane & 31;
    const int half = lane >> 5;
    const int wm = (wave >> 1) * 128;    // wave's m offset (0 or 128)
    const int wn = (wave & 1) * 64;      // wave's n offset (0 or 64)

    // XCD-aware bijective swizzle: 1536 blocks = 8 XCDs x 192
    // (12 B-panels x 16 M-tiles per XCD chunk; B-panel L2-resident).
    const int bid = blockIdx.y * 16 + blockIdx.x;   // x fastest at dispatch
    const int sw  = (bid & 7) * 192 + (bid >> 3);
    const int bm0 = (sw & 15) * BM;                  // M fastest within chunk
    const int bn0 = (sw >> 4) * BN;

    // ---- A staging constants (round-0 verbatim) ----
    const int rowInChunk = lane >> 3;                 // 0..7
    const int slot       = lane & 7;
    const int gread      = (l32 & 7) ^ (((l32 >> 3) & 3) << 1);

    // ---- fused-B constants ----
    const int brow = tid >> 1;                        // 0..127 (B row in tile)
    const int hk   = tid & 1;                         // k-half (32 elems)
    const int gr   = (brow & 7) ^ (((brow >> 3) & 3) << 1);
    const int ncol = bn0 + brow;                      // output col / Q row
    const int* qrow = Q + (size_t)ncol * (K_DIM / 2) + hk * 16;

    floatx16 acc[4][2] = {};

    // Dequant one int4 (4 int32, 1 byte each = 8 nibbles) -> one bf16x8,
    // store into DST (= Bs[buf] + brow*64) at the swizzled slot for frag J.
    #define DQW(Q4, J, DST, S, Z) { bf16x8 o; \
        o[0] = (__bf16)(((float)((Q4).x & 15)        - (Z)) * (S)); \
        o[1] = (__bf16)(((float)(((Q4).x >> 4) & 15) - (Z)) * (S)); \
        o[2] = (__bf16)(((float)((Q4).y & 15)        - (Z)) * (S)); \
        o[3] = (__bf16)(((float)(((Q4).y >> 4) & 15) - (Z)) * (S)); \
        o[4] = (__bf16)(((float)((Q4).z & 15)        - (Z)) * (S)); \
        o[5] = (__bf16)(((float)(((Q4).z >> 4) & 15) - (Z)) * (S)); \
        o[6] = (__bf16)(((float)((Q4).w & 15)        - (Z)) * (S)); \
        o[7] = (__bf16)(((float)(((Q4).w >> 4) & 15) - (Z)) * (S)); \
        *(bf16x8*)((DST) + (((hk * 4 + (J)) ^ gr) << 3)) = o; }

    // Prologue: dequant tile 0 into Bs[0] (writes drain at first barrier).
    {
        int4 p0 = *(const int4*)(qrow + 0);
        int4 p1 = *(const int4*)(qrow + 4);
        int4 p2 = *(const int4*)(qrow + 8);
        int4 p3 = *(const int4*)(qrow + 12);
        float sp = scales[ncol];     // group 0
        float zp = zeros[ncol];
        __bf16* d0 = &Bs[0][brow * 64];
        DQW(p0, 0, d0, sp, zp); DQW(p1, 1, d0, sp, zp);
        DQW(p2, 2, d0, sp, zp); DQW(p3, 3, d0, sp, zp);
    }
    // qcur = tile 1 (group (1>>1) = 0)
    int4 qc0 = *(const int4*)(qrow + 32);
    int4 qc1 = *(const int4*)(qrow + 36);
    int4 qc2 = *(const int4*)(qrow + 40);
    int4 qc3 = *(const int4*)(qrow + 44);
    float sc = scales[ncol];
    float zc = zeros[ncol];

    for (int kt = 0; kt < NT; ++kt) {
        const int cur = kt & 1;
        const int nxt = cur ^ 1;
        const int k0  = kt * BK;
        // A: 32 chunks of 8 rows; 8 per wave (global_load_lds, pre-swizzled src)
        #pragma unroll
        for (int r = 0; r < 8; ++r) {
            const int chunk = wave * 8 + r;
            const int row   = chunk * 8 + rowInChunk;
            const int kblk  = slot ^ rowInChunk ^ ((r & 3) << 1);
            const __bf16* ga = A + (size_t)(bm0 + row) * K_DIM + k0 + kblk * 8;
            __builtin_amdgcn_global_load_lds(
                (const __attribute__((address_space(1))) void*)ga,
                (__attribute__((address_space(3))) void*)(As + chunk * 512), 16, 0, 0);
        }
        __syncthreads();   // A DMA drained; Bs[cur] writes (prev compute) drained

        // Issue q prefetch for tile kt+2: lands during this compute phase.
        const int kn2 = (kt + 2) & (NT - 1);           // wrap: dead data, in-bounds
        const int cb  = kn2 * 32;
        int4 qn0 = *(const int4*)(qrow + cb + 0);
        int4 qn1 = *(const int4*)(qrow + cb + 4);
        int4 qn2 = *(const int4*)(qrow + cb + 8);
        int4 qn3 = *(const int4*)(qrow + cb + 12);
        float sn = scales[(kn2 >> 1) * N_DIM + ncol];
        float zn = zeros[(kn2 >> 1) * N_DIM + ncol];

        // Compute tile kt from As + Bs[cur]; interleave DQW(kt+1) -> Bs[nxt].
        __bf16* bnx = &Bs[nxt][brow * 64];
        #pragma unroll
        for (int ks = 0; ks < 4; ++ks) {              // 4 k-steps of 16
            const int blk = ks * 2 + half;            // logical 16B-block along BK
            const int off = (blk ^ gread) << 3;       // swizzled element offset
            bf16x8 af[4], bfr[2];
            #pragma unroll
            for (int i = 0; i < 4; ++i)
                af[i] = *(const bf16x8*)(As + (wm + i * 32 + l32) * BK + off);
            #pragma unroll
            for (int t = 0; t < 2; ++t)
                bfr[t] = *(const bf16x8*)(&Bs[cur][0] + (wn + t * 32 + l32) * BK + off);
            if (ks == 0) DQW(qc0, 0, bnx, sc, zc);
            if (ks == 1) DQW(qc1, 1, bnx, sc, zc);
            if (ks == 2) DQW(qc2, 2, bnx, sc, zc);
            if (ks == 3) DQW(qc3, 3, bnx, sc, zc);
            #pragma unroll
            for (int mi = 0; mi < 4; ++mi)
                #pragma unroll
                for (int ni = 0; ni < 2; ++ni)
                    acc[mi][ni] = __builtin_amdgcn_mfma_f32_32x32x16_bf16(
                        af[mi], bfr[ni], acc[mi][ni], 0, 0, 0);
        }
        __syncthreads();   // As/Bs[nxt] consumers+producers aligned for next iter

        qc0 = qn0; qc1 = qn1; qc2 = qn2; qc3 = qn3;
        sc = sn; zc = zn;
    }

    // Epilogue: 32x32 C/D layout: col = lane&31, row = (reg&3)+8*(reg>>2)+4*half.
    #pragma unroll
    for (int ni = 0; ni < 2; ++ni) {
        const int col = bn0 + wn + ni * 32 + l32;
        const float bv = bias[col];
        #pragma unroll
        for (int mi = 0; mi < 4; ++mi) {
            #pragma unroll
            for (int reg = 0; reg < 16; ++reg) {
                const int row = bm0 + wm + mi * 32 + half * 4 + (reg & 3) + 8 * (reg >> 2);
                C[(size_t)row * N_DIM + col] = acc[mi][ni][reg] + bv;
            }
        }
    }
}

extern "C" void kernel_launch(void* const* d_in, const int* in_sizes, int n_in,
                              void* d_out, int out_size, void* d_ws, size_t ws_size,
                              hipStream_t stream) {
    const float* x      = (const float*)d_in[0];
    const int*   qw     = (const int*)d_in[1];
    const float* scales = (const float*)d_in[2];
    const float* zeros  = (const float*)d_in[3];
    const float* bias   = (const float*)d_in[4];
    float* out = (float*)d_out;

    // Workspace: [xb: M*K bf16 = 32 MiB] (dequant workspace eliminated)
    __bf16* xb = (__bf16*)d_ws;

    xcast_kernel<<<(M_DIM * K_DIM / 8) / 256, 256, 0, stream>>>(x, xb);

    dim3 grid(M_DIM / BM, N_DIM / BN);   // (16, 96)
    gemm_kernel<<<grid, 256, 0, stream>>>(xb, qw, scales, zeros, bias, out);
}